// Round 1
// baseline (1183.030 us; speedup 1.0000x reference)
//
#include <hip/hip_runtime.h>

#define NN 50000
#define NE 400000
#define NB 128

// ============================ CSR build ============================
__global__ __launch_bounds__(256) void k_hist(const int* __restrict__ dstv, int* __restrict__ deg) {
    int e = blockIdx.x * 256 + threadIdx.x;
    if (e < NE) atomicAdd(&deg[dstv[e]], 1);
}

__global__ __launch_bounds__(1024) void k_scan(const int* __restrict__ deg, int* __restrict__ rowptr) {
    __shared__ int wsum[16];
    __shared__ int total_s;
    const int tid = threadIdx.x, lane = tid & 63, w = tid >> 6;
    if (tid == 0) rowptr[0] = 0;
    int carry = 0;
    for (int base = 0; base < NN; base += 1024) {
        int i = base + tid;
        int v = (i < NN) ? deg[i] : 0;
        int incl = v;
        #pragma unroll
        for (int off = 1; off < 64; off <<= 1) {
            int t = __shfl_up(incl, off);
            if (lane >= off) incl += t;
        }
        if (lane == 63) wsum[w] = incl;
        __syncthreads();
        if (tid < 16) {
            int s = wsum[tid];
            int si = s;
            #pragma unroll
            for (int off = 1; off < 16; off <<= 1) {
                int t = __shfl_up(si, off, 16);
                if (tid >= off) si += t;
            }
            wsum[tid] = si - s;          // exclusive offset of this wave
            if (tid == 15) total_s = si; // chunk total
        }
        __syncthreads();
        if (i < NN) rowptr[i + 1] = carry + wsum[w] + incl;
        carry += total_s;
        __syncthreads();
    }
}

__global__ __launch_bounds__(256) void k_scatter(const int* __restrict__ dstv, const int* __restrict__ rowptr,
                                                 int* __restrict__ cnt, int* __restrict__ eid) {
    int e = blockIdx.x * 256 + threadIdx.x;
    if (e < NE) {
        int d = dstv[e];
        int pos = rowptr[d] + atomicAdd(&cnt[d], 1);
        eid[pos] = e;
    }
}

// ============================ GEMM: [N,64] @ [64,256] -> [N,256] ============================
__global__ __launch_bounds__(256) void k_gemm64(const float* __restrict__ A, const float* __restrict__ W,
                                                float* __restrict__ C) {
    __shared__ float Ws[64 * 256]; // 64KB
    for (int i = threadIdx.x; i < 64 * 256 / 4; i += 256)
        ((float4*)Ws)[i] = ((const float4*)W)[i];
    __syncthreads();
    const int cg = threadIdx.x & 31; // cols cg*4..+3 and 128+cg*4..+3
    const int rq = threadIdx.x >> 5; // 0..7
    const int r0 = blockIdx.x * 32 + rq * 4;
    float acc[4][8];
    #pragma unroll
    for (int a = 0; a < 4; ++a)
        #pragma unroll
        for (int b = 0; b < 8; ++b) acc[a][b] = 0.f;

    for (int kq = 0; kq < 16; ++kq) {
        float4 av[4];
        #pragma unroll
        for (int rr = 0; rr < 4; ++rr) {
            int r = r0 + rr;
            av[rr] = (r < NN) ? ((const float4*)A)[r * 16 + kq] : make_float4(0.f, 0.f, 0.f, 0.f);
        }
#define GSTEP(COMP, K)                                                    \
        {                                                                 \
            const int k_ = (K);                                           \
            const float4 w0 = *(const float4*)(Ws + k_ * 256 + cg * 4);   \
            const float4 w1 = *(const float4*)(Ws + k_ * 256 + 128 + cg * 4); \
            _Pragma("unroll")                                             \
            for (int rr = 0; rr < 4; ++rr) {                              \
                const float a = av[rr].COMP;                              \
                acc[rr][0] = fmaf(a, w0.x, acc[rr][0]);                   \
                acc[rr][1] = fmaf(a, w0.y, acc[rr][1]);                   \
                acc[rr][2] = fmaf(a, w0.z, acc[rr][2]);                   \
                acc[rr][3] = fmaf(a, w0.w, acc[rr][3]);                   \
                acc[rr][4] = fmaf(a, w1.x, acc[rr][4]);                   \
                acc[rr][5] = fmaf(a, w1.y, acc[rr][5]);                   \
                acc[rr][6] = fmaf(a, w1.z, acc[rr][6]);                   \
                acc[rr][7] = fmaf(a, w1.w, acc[rr][7]);                   \
            }                                                             \
        }
        GSTEP(x, kq * 4 + 0)
        GSTEP(y, kq * 4 + 1)
        GSTEP(z, kq * 4 + 2)
        GSTEP(w, kq * 4 + 3)
#undef GSTEP
    }
    #pragma unroll
    for (int rr = 0; rr < 4; ++rr) {
        int r = r0 + rr;
        if (r < NN) {
            float4 o0 = make_float4(acc[rr][0], acc[rr][1], acc[rr][2], acc[rr][3]);
            float4 o1 = make_float4(acc[rr][4], acc[rr][5], acc[rr][6], acc[rr][7]);
            *(float4*)(C + r * 256 + cg * 4) = o0;
            *(float4*)(C + r * 256 + 128 + cg * 4) = o1;
        }
    }
}

// ============================ Fused edge kernel: per-dst online softmax + aggregate ============================
// wave per node; lane L owns channels 4L..4L+3 (head = L/16); online softmax per 16-lane head group.
__global__ __launch_bounds__(1024) void k_agg(const float* __restrict__ xl, const float* __restrict__ hin,
                                              const float* __restrict__ Wr, const float* __restrict__ Wes,
                                              const float* __restrict__ att, const float* __restrict__ gatb,
                                              const int* __restrict__ rowptr, const int* __restrict__ eidb,
                                              const int* __restrict__ srcv, const float* __restrict__ eattr,
                                              float* __restrict__ agg) {
    __shared__ float We_s[8 * 256]; // 8KB
    for (int i = threadIdx.x; i < 8 * 256 / 4; i += blockDim.x)
        ((float4*)We_s)[i] = ((const float4*)Wes)[i];
    __syncthreads();
    const int lane = threadIdx.x & 63;
    const int nw = (int)(gridDim.x * (blockDim.x >> 6));
    int wid = blockIdx.x * (blockDim.x >> 6) + (threadIdx.x >> 6);
    const float4 attf = ((const float4*)att)[lane];
    const float4 gbf = ((const float4*)gatb)[lane];

    for (int n = wid; n < NN; n += nw) {
        // xr[n][4L..4L+3] on the fly: h[n] @ Wr
        float hv = hin[n * 64 + lane];
        float xr0 = 0.f, xr1 = 0.f, xr2 = 0.f, xr3 = 0.f;
        for (int k = 0; k < 64; ++k) {
            float hk = __shfl(hv, k);
            const float4 w = ((const float4*)(Wr + k * 256))[lane];
            xr0 = fmaf(hk, w.x, xr0);
            xr1 = fmaf(hk, w.y, xr1);
            xr2 = fmaf(hk, w.z, xr2);
            xr3 = fmaf(hk, w.w, xr3);
        }
        const int e0 = rowptr[n], e1 = rowptr[n + 1];
        float mrun = -__builtin_inff(), den = 0.f;
        float a0 = 0.f, a1 = 0.f, a2 = 0.f, a3 = 0.f;
        for (int ei = e0; ei < e1; ++ei) {
            const int e = eidb[ei];
            const int s = srcv[e];
            const float4 xls = ((const float4*)(xl + s * 256))[lane];
            const float4 ar0 = ((const float4*)(eattr + e * 8))[0];
            const float4 ar1 = ((const float4*)(eattr + e * 8))[1];
            float e0c = 0.f, e1c = 0.f, e2c = 0.f, e3c = 0.f;
            const float avv[8] = {ar0.x, ar0.y, ar0.z, ar0.w, ar1.x, ar1.y, ar1.z, ar1.w};
            #pragma unroll
            for (int d = 0; d < 8; ++d) {
                const float4 w = ((const float4*)(We_s + d * 256))[lane];
                e0c = fmaf(avv[d], w.x, e0c);
                e1c = fmaf(avv[d], w.y, e1c);
                e2c = fmaf(avv[d], w.z, e2c);
                e3c = fmaf(avv[d], w.w, e3c);
            }
            float v0 = xls.x + xr0 + e0c;
            float v1 = xls.y + xr1 + e1c;
            float v2 = xls.z + xr2 + e2c;
            float v3 = xls.w + xr3 + e3c;
            // leaky_relu(v, 0.2) = max(v, 0.2v)
            v0 = fmaxf(v0, 0.2f * v0);
            v1 = fmaxf(v1, 0.2f * v1);
            v2 = fmaxf(v2, 0.2f * v2);
            v3 = fmaxf(v3, 0.2f * v3);
            float part = v0 * attf.x + v1 * attf.y + v2 * attf.z + v3 * attf.w;
            part += __shfl_xor(part, 1);
            part += __shfl_xor(part, 2);
            part += __shfl_xor(part, 4);
            part += __shfl_xor(part, 8);
            const float mn = fmaxf(mrun, part);
            const float sc = __expf(mrun - mn); // exp(-inf)=0 on first edge
            const float p = __expf(part - mn);
            den = den * sc + p;
            a0 = fmaf(a0, sc, p * xls.x);
            a1 = fmaf(a1, sc, p * xls.y);
            a2 = fmaf(a2, sc, p * xls.z);
            a3 = fmaf(a3, sc, p * xls.w);
            mrun = mn;
        }
        const float inv = (e1 > e0) ? (1.0f / den) : 0.f;
        float4 o;
        o.x = fmaf(a0, inv, gbf.x);
        o.y = fmaf(a1, inv, gbf.y);
        o.z = fmaf(a2, inv, gbf.z);
        o.w = fmaf(a3, inv, gbf.w);
        ((float4*)(agg + n * 256))[lane] = o;
    }
}

// ============================ tr GEMM: [N,256]@[256,64] + bias, relu, BN stats ============================
__global__ __launch_bounds__(256) void k_tr(const float* __restrict__ A, const float* __restrict__ W,
                                            const float* __restrict__ bias, float* __restrict__ Hout,
                                            float* __restrict__ stats) {
    __shared__ float Ws[256 * 64]; // 64KB; reused for stats reduction at the end
    for (int i = threadIdx.x; i < 256 * 64 / 4; i += 256)
        ((float4*)Ws)[i] = ((const float4*)W)[i];
    __syncthreads();
    const int cg = threadIdx.x & 7;  // cols cg*4..+3 and 32+cg*4..+3
    const int rq = threadIdx.x >> 3; // 0..31
    const int r0 = blockIdx.x * 128 + rq * 4;
    float b8[8];
    #pragma unroll
    for (int j = 0; j < 8; ++j) b8[j] = bias[(j < 4) ? (cg * 4 + j) : (32 + cg * 4 + (j - 4))];
    float acc[4][8];
    #pragma unroll
    for (int a = 0; a < 4; ++a)
        #pragma unroll
        for (int b = 0; b < 8; ++b) acc[a][b] = b8[b];

    for (int kq = 0; kq < 64; ++kq) {
        float4 av[4];
        #pragma unroll
        for (int rr = 0; rr < 4; ++rr) {
            int r = r0 + rr;
            av[rr] = (r < NN) ? ((const float4*)A)[r * 64 + kq] : make_float4(0.f, 0.f, 0.f, 0.f);
        }
#define TSTEP(COMP, K)                                                    \
        {                                                                 \
            const int k_ = (K);                                           \
            const float4 w0 = *(const float4*)(Ws + k_ * 64 + cg * 4);    \
            const float4 w1 = *(const float4*)(Ws + k_ * 64 + 32 + cg * 4); \
            _Pragma("unroll")                                             \
            for (int rr = 0; rr < 4; ++rr) {                              \
                const float a = av[rr].COMP;                              \
                acc[rr][0] = fmaf(a, w0.x, acc[rr][0]);                   \
                acc[rr][1] = fmaf(a, w0.y, acc[rr][1]);                   \
                acc[rr][2] = fmaf(a, w0.z, acc[rr][2]);                   \
                acc[rr][3] = fmaf(a, w0.w, acc[rr][3]);                   \
                acc[rr][4] = fmaf(a, w1.x, acc[rr][4]);                   \
                acc[rr][5] = fmaf(a, w1.y, acc[rr][5]);                   \
                acc[rr][6] = fmaf(a, w1.z, acc[rr][6]);                   \
                acc[rr][7] = fmaf(a, w1.w, acc[rr][7]);                   \
            }                                                             \
        }
        TSTEP(x, kq * 4 + 0)
        TSTEP(y, kq * 4 + 1)
        TSTEP(z, kq * 4 + 2)
        TSTEP(w, kq * 4 + 3)
#undef TSTEP
    }
    float lsum[8], lsq[8];
    #pragma unroll
    for (int j = 0; j < 8; ++j) { lsum[j] = 0.f; lsq[j] = 0.f; }
    #pragma unroll
    for (int rr = 0; rr < 4; ++rr) {
        int r = r0 + rr;
        if (r < NN) {
            float v[8];
            #pragma unroll
            for (int j = 0; j < 8; ++j) {
                v[j] = fmaxf(acc[rr][j], 0.f);
                lsum[j] += v[j];
                lsq[j] = fmaf(v[j], v[j], lsq[j]);
            }
            *(float4*)(Hout + r * 64 + cg * 4) = make_float4(v[0], v[1], v[2], v[3]);
            *(float4*)(Hout + r * 64 + 32 + cg * 4) = make_float4(v[4], v[5], v[6], v[7]);
        }
    }
    // stats reduction (reuse Ws)
    __syncthreads();
    if (threadIdx.x < 128) Ws[threadIdx.x] = 0.f;
    __syncthreads();
    #pragma unroll
    for (int j = 0; j < 8; ++j) {
        int c = (j < 4) ? (cg * 4 + j) : (32 + cg * 4 + (j - 4));
        atomicAdd(&Ws[c], lsum[j]);
        atomicAdd(&Ws[64 + c], lsq[j]);
    }
    __syncthreads();
    if (threadIdx.x < 64) {
        atomicAdd(&stats[threadIdx.x], Ws[threadIdx.x]);
        atomicAdd(&stats[64 + threadIdx.x], Ws[64 + threadIdx.x]);
    }
}

__global__ void k_bn_finalize(float* __restrict__ stats, const float* __restrict__ g, const float* __restrict__ b) {
    const int c = threadIdx.x; // 64 threads
    const float mu = stats[c] * (1.0f / (float)NN);
    const float var = stats[64 + c] * (1.0f / (float)NN) - mu * mu;
    const float rstd = rsqrtf(var + 1e-5f);
    const float sc = g[c] * rstd;
    stats[128 + c] = sc;
    stats[192 + c] = fmaf(-mu, sc, b[c]);
}

__global__ __launch_bounds__(256) void k_bn_apply(float* __restrict__ h, const float* __restrict__ stats) {
    const int i = blockIdx.x * 256 + threadIdx.x; // exactly N*16
    const int cq = i & 15;
    float4 v = ((float4*)h)[i];
    const float4 sc = ((const float4*)(stats + 128))[cq];
    const float4 sh = ((const float4*)(stats + 192))[cq];
    v.x = fmaf(v.x, sc.x, sh.x);
    v.y = fmaf(v.y, sc.y, sh.y);
    v.z = fmaf(v.z, sc.z, sh.z);
    v.w = fmaf(v.w, sc.w, sh.w);
    ((float4*)h)[i] = v;
}

// ============================ pooling ============================
__global__ __launch_bounds__(256) void k_gate(const float* __restrict__ h, const float* __restrict__ gw,
                                              const float* __restrict__ gb, float* __restrict__ gate) {
    const int lane = threadIdx.x & 63;
    const int node = blockIdx.x * 4 + (threadIdx.x >> 6); // exact: 12500*4 = 50000
    float p = h[node * 64 + lane] * gw[lane];
    #pragma unroll
    for (int off = 32; off; off >>= 1) p += __shfl_xor(p, off);
    if (lane == 0) gate[node] = p + gb[0];
}

__global__ __launch_bounds__(256) void k_pool(float* __restrict__ gate, const float* __restrict__ h,
                                              const int* __restrict__ bidx, float* __restrict__ pooled) {
    __shared__ float red[4];
    __shared__ float pp[4][64];
    const int b = blockIdx.x, tid = threadIdx.x, lane = tid & 63, w = tid >> 6;
    int lo = 0, hi = NN;
    while (lo < hi) { int mid = (lo + hi) >> 1; if (bidx[mid] < b) lo = mid + 1; else hi = mid; }
    const int s0 = lo;
    lo = 0; hi = NN;
    while (lo < hi) { int mid = (lo + hi) >> 1; if (bidx[mid] < b + 1) lo = mid + 1; else hi = mid; }
    const int s1 = lo;
    if (s1 == s0) {
        if (tid < 64) pooled[b * 64 + tid] = 0.f;
        return;
    }
    float v = -__builtin_inff();
    for (int i = s0 + tid; i < s1; i += 256) v = fmaxf(v, gate[i]);
    #pragma unroll
    for (int off = 32; off; off >>= 1) v = fmaxf(v, __shfl_xor(v, off));
    if (lane == 0) red[w] = v;
    __syncthreads();
    const float mx = fmaxf(fmaxf(red[0], red[1]), fmaxf(red[2], red[3]));
    __syncthreads();
    float d = 0.f;
    for (int i = s0 + tid; i < s1; i += 256) {
        const float ex = __expf(gate[i] - mx);
        gate[i] = ex;
        d += ex;
    }
    #pragma unroll
    for (int off = 32; off; off >>= 1) d += __shfl_xor(d, off);
    if (lane == 0) red[w] = d;
    __syncthreads();
    const float den = red[0] + red[1] + red[2] + red[3];
    const int c = tid & 63, ro = tid >> 6;
    float acc = 0.f;
    for (int i = s0 + ro; i < s1; i += 4) acc = fmaf(gate[i], h[i * 64 + c], acc);
    pp[ro][c] = acc;
    __syncthreads();
    if (ro == 0) {
        const float tot = pp[0][c] + pp[1][c] + pp[2][c] + pp[3][c];
        pooled[b * 64 + c] = tot / den;
    }
}

// ============================ MLP head ============================
__global__ __launch_bounds__(256) void k_head(const float* __restrict__ pooled, const float* __restrict__ fc,
                                              const float* __restrict__ nrot, const float* __restrict__ W1,
                                              const float* __restrict__ b1, const float* __restrict__ W2,
                                              const float* __restrict__ b2, const float* __restrict__ W3,
                                              const float* __restrict__ b3, const float* __restrict__ W4,
                                              const float* __restrict__ b4, float* __restrict__ out) {
    __shared__ float z[66], a1[256], a2[128], a3[64];
    const int b = blockIdx.x, tid = threadIdx.x;
    if (tid < 64) z[tid] = pooled[b * 64 + tid];
    if (tid == 64) z[64] = fc[b];
    if (tid == 65) z[65] = nrot[b];
    __syncthreads();
    float s = b1[tid];
    for (int k = 0; k < 66; ++k) s = fmaf(z[k], W1[k * 256 + tid], s);
    a1[tid] = fmaxf(s, 0.f);
    __syncthreads();
    if (tid < 128) {
        float s2 = b2[tid];
        for (int k = 0; k < 256; ++k) s2 = fmaf(a1[k], W2[k * 128 + tid], s2);
        a2[tid] = fmaxf(s2, 0.f);
    }
    __syncthreads();
    if (tid < 64) {
        float s3 = b3[tid];
        for (int k = 0; k < 128; ++k) s3 = fmaf(a2[k], W3[k * 64 + tid], s3);
        a3[tid] = fmaxf(s3, 0.f);
    }
    __syncthreads();
    if (tid < 64) {
        float p = a3[tid] * W4[tid];
        #pragma unroll
        for (int off = 32; off; off >>= 1) p += __shfl_xor(p, off);
        if (tid == 0) out[b] = p + b4[0];
    }
}

// ============================ launch ============================
extern "C" void kernel_launch(void* const* d_in, const int* in_sizes, int n_in,
                              void* d_out, int out_size, void* d_ws, size_t ws_size,
                              hipStream_t stream) {
    const float* x     = (const float*)d_in[0];
    const int*   ei    = (const int*)d_in[1];
    const float* eattr = (const float*)d_in[2];
    const float* fc    = (const float*)d_in[3];
    const float* nrot  = (const float*)d_in[4];
    const int*   bidx  = (const int*)d_in[5];
    const float* Wl    = (const float*)d_in[6];
    const float* Wr    = (const float*)d_in[7];
    const float* We    = (const float*)d_in[8];
    const float* att   = (const float*)d_in[9];
    const float* gatb  = (const float*)d_in[10];
    const float* trW   = (const float*)d_in[11];
    const float* trb   = (const float*)d_in[12];
    const float* bng   = (const float*)d_in[13];
    const float* bnb   = (const float*)d_in[14];
    const float* gateW = (const float*)d_in[15];
    const float* gateB = (const float*)d_in[16];
    const float* W1    = (const float*)d_in[17];
    const float* b1    = (const float*)d_in[18];
    const float* W2    = (const float*)d_in[19];
    const float* b2    = (const float*)d_in[20];
    const float* W3    = (const float*)d_in[21];
    const float* b3    = (const float*)d_in[22];
    const float* W4    = (const float*)d_in[23];
    const float* b4    = (const float*)d_in[24];
    float* out = (float*)d_out;

    const int* srcv = ei;
    const int* dstv = ei + NE;

    char* w = (char*)d_ws;
    float* xl     = (float*)(w + 0);          // 51,200,000
    float* agg    = (float*)(w + 51200000);   // 51,200,000
    float* hbuf   = (float*)(w + 102400000);  // 12,800,000
    int*   deg    = (int*)  (w + 115200000);  // 200,000
    int*   cnt    = (int*)  (w + 115400000);  // 200,000
    int*   rowptr = (int*)  (w + 115600000);  // 200,004
    int*   eid    = (int*)  (w + 115800064);  // 1,600,000
    float* gate   = (float*)(w + 117400064);  // 200,000
    float* stats  = (float*)(w + 117600064);  // 1,024
    float* pooled = (float*)(w + 117601088);  // 32,768  -> total 117,633,856 B

    hipMemsetAsync(deg, 0, NN * 4, stream);
    hipMemsetAsync(cnt, 0, NN * 4, stream);
    k_hist<<<(NE + 255) / 256, 256, 0, stream>>>(dstv, deg);
    k_scan<<<1, 1024, 0, stream>>>(deg, rowptr);
    k_scatter<<<(NE + 255) / 256, 256, 0, stream>>>(dstv, rowptr, cnt, eid);

    const float* hin = x;
    for (int l = 0; l < 3; ++l) {
        k_gemm64<<<(NN + 31) / 32, 256, 0, stream>>>(hin, Wl + l * 64 * 256, xl);
        hipMemsetAsync(stats, 0, 128 * 4, stream);
        k_agg<<<512, 1024, 0, stream>>>(xl, hin, Wr + l * 64 * 256, We + l * 8 * 256, att + l * 256,
                                        gatb + l * 256, rowptr, eid, srcv, eattr, agg);
        k_tr<<<(NN + 127) / 128, 256, 0, stream>>>(agg, trW + l * 256 * 64, trb + l * 64, hbuf, stats);
        k_bn_finalize<<<1, 64, 0, stream>>>(stats, bng + l * 64, bnb + l * 64);
        k_bn_apply<<<(NN * 16) / 256, 256, 0, stream>>>(hbuf, stats);
        hin = hbuf;
    }
    k_gate<<<NN / 4, 256, 0, stream>>>(hbuf, gateW, gateB, gate);
    k_pool<<<NB, 256, 0, stream>>>(gate, hbuf, bidx, pooled);
    k_head<<<NB, 256, 0, stream>>>(pooled, fc, nrot, W1, b1, W2, b2, W3, b3, W4, b4, out);
}

// Round 2
// 1016.738 us; speedup vs baseline: 1.1636x; 1.1636x over previous
//
#include <hip/hip_runtime.h>

#define NN 50000
#define NE 400000
#define NB 128
#define NINF (-__builtin_inff())

// ============================ CSR build ============================
__global__ __launch_bounds__(256) void k_hist(const int* __restrict__ dstv, int* __restrict__ deg) {
    int e = blockIdx.x * 256 + threadIdx.x;
    if (e < NE) atomicAdd(&deg[dstv[e]], 1);
}

__global__ __launch_bounds__(1024) void k_scan(const int* __restrict__ deg, int* __restrict__ rowptr) {
    __shared__ int wsum[16];
    __shared__ int total_s;
    const int tid = threadIdx.x, lane = tid & 63, w = tid >> 6;
    if (tid == 0) rowptr[0] = 0;
    int carry = 0;
    for (int base = 0; base < NN; base += 1024) {
        int i = base + tid;
        int v = (i < NN) ? deg[i] : 0;
        int incl = v;
        #pragma unroll
        for (int off = 1; off < 64; off <<= 1) {
            int t = __shfl_up(incl, off);
            if (lane >= off) incl += t;
        }
        if (lane == 63) wsum[w] = incl;
        __syncthreads();
        if (tid < 16) {
            int s = wsum[tid];
            int si = s;
            #pragma unroll
            for (int off = 1; off < 16; off <<= 1) {
                int t = __shfl_up(si, off, 16);
                if (tid >= off) si += t;
            }
            wsum[tid] = si - s;
            if (tid == 15) total_s = si;
        }
        __syncthreads();
        if (i < NN) rowptr[i + 1] = carry + wsum[w] + incl;
        carry += total_s;
        __syncthreads();
    }
}

__global__ __launch_bounds__(256) void k_scatter(const int* __restrict__ dstv, const int* __restrict__ rowptr,
                                                 int* __restrict__ cnt, int* __restrict__ eid) {
    int e = blockIdx.x * 256 + threadIdx.x;
    if (e < NE) {
        int d = dstv[e];
        int pos = rowptr[d] + atomicAdd(&cnt[d], 1);
        eid[pos] = e;
    }
}

// ============================ GEMM: [N,64] @ [64,256] -> xl and xr (blockIdx.y) ============================
// BN of previous layer folded in: W_staged = diag(sc)*W, acc init = (sh @ W)[col]
__global__ __launch_bounds__(256) void k_gemm64(const float* __restrict__ A, const float* __restrict__ Wl,
                                                const float* __restrict__ Wr, float* __restrict__ Cl,
                                                float* __restrict__ Cr, const float* __restrict__ bnp) {
    __shared__ float Ws[64 * 256]; // 64KB
    const float* W = blockIdx.y ? Wr : Wl;
    float* C = blockIdx.y ? Cr : Cl;
    for (int i = threadIdx.x; i < 4096; i += 256) {
        float4 v = ((const float4*)W)[i];
        if (bnp) {
            const float s = bnp[128 + (i >> 6)];
            v.x *= s; v.y *= s; v.z *= s; v.w *= s;
        }
        ((float4*)Ws)[i] = v;
    }
    __syncthreads();
    const int cg = threadIdx.x & 31; // cols cg*4..+3 and 128+cg*4..+3
    const int rq = threadIdx.x >> 5; // 0..7
    const int r0 = blockIdx.x * 32 + rq * 4;
    float init8[8];
    if (bnp) {
        const float* shW = bnp + 256 + (blockIdx.y ? 256 : 0);
        #pragma unroll
        for (int j = 0; j < 8; ++j) init8[j] = shW[(j < 4) ? (cg * 4 + j) : (128 + cg * 4 + (j - 4))];
    } else {
        #pragma unroll
        for (int j = 0; j < 8; ++j) init8[j] = 0.f;
    }
    float acc[4][8];
    #pragma unroll
    for (int a = 0; a < 4; ++a)
        #pragma unroll
        for (int b = 0; b < 8; ++b) acc[a][b] = init8[b];

    for (int kq = 0; kq < 16; ++kq) {
        float4 av[4];
        #pragma unroll
        for (int rr = 0; rr < 4; ++rr) {
            int r = r0 + rr;
            av[rr] = (r < NN) ? ((const float4*)A)[r * 16 + kq] : make_float4(0.f, 0.f, 0.f, 0.f);
        }
#define GSTEP(COMP, K)                                                    \
        {                                                                 \
            const int k_ = (K);                                           \
            const float4 w0 = *(const float4*)(Ws + k_ * 256 + cg * 4);   \
            const float4 w1 = *(const float4*)(Ws + k_ * 256 + 128 + cg * 4); \
            _Pragma("unroll")                                             \
            for (int rr = 0; rr < 4; ++rr) {                              \
                const float a = av[rr].COMP;                              \
                acc[rr][0] = fmaf(a, w0.x, acc[rr][0]);                   \
                acc[rr][1] = fmaf(a, w0.y, acc[rr][1]);                   \
                acc[rr][2] = fmaf(a, w0.z, acc[rr][2]);                   \
                acc[rr][3] = fmaf(a, w0.w, acc[rr][3]);                   \
                acc[rr][4] = fmaf(a, w1.x, acc[rr][4]);                   \
                acc[rr][5] = fmaf(a, w1.y, acc[rr][5]);                   \
                acc[rr][6] = fmaf(a, w1.z, acc[rr][6]);                   \
                acc[rr][7] = fmaf(a, w1.w, acc[rr][7]);                   \
            }                                                             \
        }
        GSTEP(x, kq * 4 + 0)
        GSTEP(y, kq * 4 + 1)
        GSTEP(z, kq * 4 + 2)
        GSTEP(w, kq * 4 + 3)
#undef GSTEP
    }
    #pragma unroll
    for (int rr = 0; rr < 4; ++rr) {
        int r = r0 + rr;
        if (r < NN) {
            *(float4*)(C + r * 256 + cg * 4) = make_float4(acc[rr][0], acc[rr][1], acc[rr][2], acc[rr][3]);
            *(float4*)(C + r * 256 + 128 + cg * 4) = make_float4(acc[rr][4], acc[rr][5], acc[rr][6], acc[rr][7]);
        }
    }
}

// ============================ Fused edge kernel ============================
// wave per node; lane L owns channels 4L..4L+3; We held in 32 regs; 3-stage prefetch pipeline.
// xragg holds xr on entry; overwritten with agg (per-row, read-before-write within the owning wave).
__global__ __launch_bounds__(256, 4) void k_agg(const float* __restrict__ xl, float* __restrict__ xragg,
                                                const float* __restrict__ att, const float* __restrict__ gatb,
                                                const int* __restrict__ rowptr, const int* __restrict__ eid,
                                                const int* __restrict__ srcv, const float* __restrict__ eattr,
                                                const float* __restrict__ We) {
    const int lane = threadIdx.x & 63;
    const float4 we0 = ((const float4*)(We + 0 * 256))[lane];
    const float4 we1 = ((const float4*)(We + 1 * 256))[lane];
    const float4 we2 = ((const float4*)(We + 2 * 256))[lane];
    const float4 we3 = ((const float4*)(We + 3 * 256))[lane];
    const float4 we4 = ((const float4*)(We + 4 * 256))[lane];
    const float4 we5 = ((const float4*)(We + 5 * 256))[lane];
    const float4 we6 = ((const float4*)(We + 6 * 256))[lane];
    const float4 we7 = ((const float4*)(We + 7 * 256))[lane];
    const float4 attf = ((const float4*)att)[lane];
    const float4 gbf = ((const float4*)gatb)[lane];
    const int nw = gridDim.x * (blockDim.x >> 6);
    int wid = blockIdx.x * (blockDim.x >> 6) + (threadIdx.x >> 6);

    for (int n = wid; n < NN; n += nw) {
        const int e0 = rowptr[n], e1 = rowptr[n + 1];
        const float4 xr = ((const float4*)(xragg + (size_t)n * 256))[lane];
        float mrun = NINF, den = 0.f;
        float a0 = 0.f, a1 = 0.f, a2 = 0.f, a3 = 0.f;
        if (e1 > e0) {
            int id0 = eid[e0];
            int id1 = (e0 + 1 < e1) ? eid[e0 + 1] : 0;
            int id2 = (e0 + 2 < e1) ? eid[e0 + 2] : 0;
            int s0 = srcv[id0];
            int s1 = (e0 + 1 < e1) ? srcv[id1] : 0;
            float4 xls_c = ((const float4*)(xl + (size_t)s0 * 256))[lane];
            float4 ea0_c = ((const float4*)(eattr + (size_t)id0 * 8))[0];
            float4 ea1_c = ((const float4*)(eattr + (size_t)id0 * 8))[1];
            for (int ei = e0; ei < e1; ++ei) {
                const bool h1 = (ei + 1 < e1), h2 = (ei + 2 < e1), h3 = (ei + 3 < e1);
                float4 xls_n = xls_c, ea0_n = ea0_c, ea1_n = ea1_c;
                int s2 = 0, id3 = 0;
                if (h1) {
                    xls_n = ((const float4*)(xl + (size_t)s1 * 256))[lane];
                    ea0_n = ((const float4*)(eattr + (size_t)id1 * 8))[0];
                    ea1_n = ((const float4*)(eattr + (size_t)id1 * 8))[1];
                }
                if (h2) s2 = srcv[id2];
                if (h3) id3 = eid[ei + 3];
                // ea @ We (rank-8, registers)
                float ec0 = ea0_c.x * we0.x, ec1 = ea0_c.x * we0.y, ec2 = ea0_c.x * we0.z, ec3 = ea0_c.x * we0.w;
                ec0 = fmaf(ea0_c.y, we1.x, ec0); ec1 = fmaf(ea0_c.y, we1.y, ec1); ec2 = fmaf(ea0_c.y, we1.z, ec2); ec3 = fmaf(ea0_c.y, we1.w, ec3);
                ec0 = fmaf(ea0_c.z, we2.x, ec0); ec1 = fmaf(ea0_c.z, we2.y, ec1); ec2 = fmaf(ea0_c.z, we2.z, ec2); ec3 = fmaf(ea0_c.z, we2.w, ec3);
                ec0 = fmaf(ea0_c.w, we3.x, ec0); ec1 = fmaf(ea0_c.w, we3.y, ec1); ec2 = fmaf(ea0_c.w, we3.z, ec2); ec3 = fmaf(ea0_c.w, we3.w, ec3);
                ec0 = fmaf(ea1_c.x, we4.x, ec0); ec1 = fmaf(ea1_c.x, we4.y, ec1); ec2 = fmaf(ea1_c.x, we4.z, ec2); ec3 = fmaf(ea1_c.x, we4.w, ec3);
                ec0 = fmaf(ea1_c.y, we5.x, ec0); ec1 = fmaf(ea1_c.y, we5.y, ec1); ec2 = fmaf(ea1_c.y, we5.z, ec2); ec3 = fmaf(ea1_c.y, we5.w, ec3);
                ec0 = fmaf(ea1_c.z, we6.x, ec0); ec1 = fmaf(ea1_c.z, we6.y, ec1); ec2 = fmaf(ea1_c.z, we6.z, ec2); ec3 = fmaf(ea1_c.z, we6.w, ec3);
                ec0 = fmaf(ea1_c.w, we7.x, ec0); ec1 = fmaf(ea1_c.w, we7.y, ec1); ec2 = fmaf(ea1_c.w, we7.z, ec2); ec3 = fmaf(ea1_c.w, we7.w, ec3);
                float v0 = xls_c.x + xr.x + ec0;
                float v1 = xls_c.y + xr.y + ec1;
                float v2 = xls_c.z + xr.z + ec2;
                float v3 = xls_c.w + xr.w + ec3;
                v0 = fmaxf(v0, 0.2f * v0);
                v1 = fmaxf(v1, 0.2f * v1);
                v2 = fmaxf(v2, 0.2f * v2);
                v3 = fmaxf(v3, 0.2f * v3);
                float part = v0 * attf.x;
                part = fmaf(v1, attf.y, part);
                part = fmaf(v2, attf.z, part);
                part = fmaf(v3, attf.w, part);
                part += __shfl_xor(part, 1);
                part += __shfl_xor(part, 2);
                part += __shfl_xor(part, 4);
                part += __shfl_xor(part, 8);
                const float mn = fmaxf(mrun, part);
                const float scl = __expf(mrun - mn); // first edge: exp(-inf)=0
                const float p = __expf(part - mn);
                den = fmaf(den, scl, p);
                a0 = fmaf(a0, scl, p * xls_c.x);
                a1 = fmaf(a1, scl, p * xls_c.y);
                a2 = fmaf(a2, scl, p * xls_c.z);
                a3 = fmaf(a3, scl, p * xls_c.w);
                mrun = mn;
                // rotate pipeline
                xls_c = xls_n; ea0_c = ea0_n; ea1_c = ea1_n;
                s1 = s2; id1 = id2; id2 = id3;
            }
        }
        const float inv = (e1 > e0) ? (1.0f / den) : 0.f;
        float4 o;
        o.x = fmaf(a0, inv, gbf.x);
        o.y = fmaf(a1, inv, gbf.y);
        o.z = fmaf(a2, inv, gbf.z);
        o.w = fmaf(a3, inv, gbf.w);
        ((float4*)(xragg + (size_t)n * 256))[lane] = o;
    }
}

// ============================ tr GEMM: [N,256]@[256,64] + bias, relu, BN stats ============================
__global__ __launch_bounds__(256) void k_tr(const float* __restrict__ A, const float* __restrict__ W,
                                            const float* __restrict__ bias, float* __restrict__ Hout,
                                            float* __restrict__ stats) {
    __shared__ float Ws[256 * 64]; // 64KB
    for (int i = threadIdx.x; i < 256 * 64 / 4; i += 256)
        ((float4*)Ws)[i] = ((const float4*)W)[i];
    __syncthreads();
    const int cg = threadIdx.x & 7;
    const int rq = threadIdx.x >> 3;
    const int r0 = blockIdx.x * 128 + rq * 4;
    float b8[8];
    #pragma unroll
    for (int j = 0; j < 8; ++j) b8[j] = bias[(j < 4) ? (cg * 4 + j) : (32 + cg * 4 + (j - 4))];
    float acc[4][8];
    #pragma unroll
    for (int a = 0; a < 4; ++a)
        #pragma unroll
        for (int b = 0; b < 8; ++b) acc[a][b] = b8[b];

    for (int kq = 0; kq < 64; ++kq) {
        float4 av[4];
        #pragma unroll
        for (int rr = 0; rr < 4; ++rr) {
            int r = r0 + rr;
            av[rr] = (r < NN) ? ((const float4*)A)[r * 64 + kq] : make_float4(0.f, 0.f, 0.f, 0.f);
        }
#define TSTEP(COMP, K)                                                    \
        {                                                                 \
            const int k_ = (K);                                           \
            const float4 w0 = *(const float4*)(Ws + k_ * 64 + cg * 4);    \
            const float4 w1 = *(const float4*)(Ws + k_ * 64 + 32 + cg * 4); \
            _Pragma("unroll")                                             \
            for (int rr = 0; rr < 4; ++rr) {                              \
                const float a = av[rr].COMP;                              \
                acc[rr][0] = fmaf(a, w0.x, acc[rr][0]);                   \
                acc[rr][1] = fmaf(a, w0.y, acc[rr][1]);                   \
                acc[rr][2] = fmaf(a, w0.z, acc[rr][2]);                   \
                acc[rr][3] = fmaf(a, w0.w, acc[rr][3]);                   \
                acc[rr][4] = fmaf(a, w1.x, acc[rr][4]);                   \
                acc[rr][5] = fmaf(a, w1.y, acc[rr][5]);                   \
                acc[rr][6] = fmaf(a, w1.z, acc[rr][6]);                   \
                acc[rr][7] = fmaf(a, w1.w, acc[rr][7]);                   \
            }                                                             \
        }
        TSTEP(x, kq * 4 + 0)
        TSTEP(y, kq * 4 + 1)
        TSTEP(z, kq * 4 + 2)
        TSTEP(w, kq * 4 + 3)
#undef TSTEP
    }
    float lsum[8], lsq[8];
    #pragma unroll
    for (int j = 0; j < 8; ++j) { lsum[j] = 0.f; lsq[j] = 0.f; }
    #pragma unroll
    for (int rr = 0; rr < 4; ++rr) {
        int r = r0 + rr;
        if (r < NN) {
            float v[8];
            #pragma unroll
            for (int j = 0; j < 8; ++j) {
                v[j] = fmaxf(acc[rr][j], 0.f);
                lsum[j] += v[j];
                lsq[j] = fmaf(v[j], v[j], lsq[j]);
            }
            *(float4*)(Hout + r * 64 + cg * 4) = make_float4(v[0], v[1], v[2], v[3]);
            *(float4*)(Hout + r * 64 + 32 + cg * 4) = make_float4(v[4], v[5], v[6], v[7]);
        }
    }
    __syncthreads();
    if (threadIdx.x < 128) Ws[threadIdx.x] = 0.f;
    __syncthreads();
    #pragma unroll
    for (int j = 0; j < 8; ++j) {
        int c = (j < 4) ? (cg * 4 + j) : (32 + cg * 4 + (j - 4));
        atomicAdd(&Ws[c], lsum[j]);
        atomicAdd(&Ws[64 + c], lsq[j]);
    }
    __syncthreads();
    if (threadIdx.x < 64) {
        atomicAdd(&stats[threadIdx.x], Ws[threadIdx.x]);
        atomicAdd(&stats[64 + threadIdx.x], Ws[64 + threadIdx.x]);
    }
}

// stats layout per layer (stride 768 floats): [0:64] sum, [64:128] sumsq, [128:192] sc,
// [192:256] sh, [256:512] sh@Wl_next, [512:768] sh@Wr_next
__global__ __launch_bounds__(256) void k_bn_finalize(float* __restrict__ st, const float* __restrict__ g,
                                                     const float* __restrict__ b, const float* __restrict__ Wln,
                                                     const float* __restrict__ Wrn) {
    __shared__ float sh_s[64];
    const int tid = threadIdx.x;
    if (tid < 64) {
        const float mu = st[tid] * (1.0f / (float)NN);
        const float var = st[64 + tid] * (1.0f / (float)NN) - mu * mu;
        const float rstd = rsqrtf(var + 1e-5f);
        const float sc = g[tid] * rstd;
        const float sh = fmaf(-mu, sc, b[tid]);
        st[128 + tid] = sc;
        st[192 + tid] = sh;
        sh_s[tid] = sh;
    }
    __syncthreads();
    if (Wln) {
        float al = 0.f, ar = 0.f;
        for (int k = 0; k < 64; ++k) {
            al = fmaf(sh_s[k], Wln[k * 256 + tid], al);
            ar = fmaf(sh_s[k], Wrn[k * 256 + tid], ar);
        }
        st[256 + tid] = al;
        st[512 + tid] = ar;
    }
}

__global__ __launch_bounds__(256) void k_bn_apply(float* __restrict__ h, const float* __restrict__ st) {
    const int i = blockIdx.x * 256 + threadIdx.x; // N*16 float4s
    const int cq = i & 15;
    float4 v = ((float4*)h)[i];
    const float4 sc = ((const float4*)(st + 128))[cq];
    const float4 sh = ((const float4*)(st + 192))[cq];
    v.x = fmaf(v.x, sc.x, sh.x);
    v.y = fmaf(v.y, sc.y, sh.y);
    v.z = fmaf(v.z, sc.z, sh.z);
    v.w = fmaf(v.w, sc.w, sh.w);
    ((float4*)h)[i] = v;
}

// ============================ fused gate + pool ============================
__global__ __launch_bounds__(256) void k_pool(const float* __restrict__ h, const float* __restrict__ gw,
                                              const int* __restrict__ bidx, float* __restrict__ pooled) {
    __shared__ float gate_s[1024];
    __shared__ float red[4];
    __shared__ float pp[4][64];
    const int b = blockIdx.x, tid = threadIdx.x, lane = tid & 63, w = tid >> 6;
    int lo = 0, hi = NN;
    while (lo < hi) { int mid = (lo + hi) >> 1; if (bidx[mid] < b) lo = mid + 1; else hi = mid; }
    const int s0 = lo;
    lo = 0; hi = NN;
    while (lo < hi) { int mid = (lo + hi) >> 1; if (bidx[mid] < b + 1) lo = mid + 1; else hi = mid; }
    const int s1 = lo;
    const int seg = s1 - s0;
    if (seg == 0) {
        if (tid < 64) pooled[b * 64 + tid] = 0.f;
        return;
    }
    const float gwv = gw[lane];
    for (int i = s0 + w; i < s1; i += 4) {
        float p = h[(size_t)i * 64 + lane] * gwv;
        #pragma unroll
        for (int off = 32; off; off >>= 1) p += __shfl_xor(p, off);
        if (lane == 0) gate_s[i - s0] = p;
    }
    __syncthreads();
    float v = NINF;
    for (int i = tid; i < seg; i += 256) v = fmaxf(v, gate_s[i]);
    #pragma unroll
    for (int off = 32; off; off >>= 1) v = fmaxf(v, __shfl_xor(v, off));
    if (lane == 0) red[w] = v;
    __syncthreads();
    const float mx = fmaxf(fmaxf(red[0], red[1]), fmaxf(red[2], red[3]));
    __syncthreads();
    float d = 0.f;
    for (int i = tid; i < seg; i += 256) {
        const float ex = __expf(gate_s[i] - mx);
        gate_s[i] = ex;
        d += ex;
    }
    #pragma unroll
    for (int off = 32; off; off >>= 1) d += __shfl_xor(d, off);
    if (lane == 0) red[w] = d;
    __syncthreads();
    const float den = red[0] + red[1] + red[2] + red[3];
    const int c = tid & 63, ro = tid >> 6;
    float acc = 0.f;
    for (int i = s0 + ro; i < s1; i += 4) acc = fmaf(gate_s[i - s0], h[(size_t)i * 64 + c], acc);
    pp[ro][c] = acc;
    __syncthreads();
    if (ro == 0) pooled[b * 64 + c] = (pp[0][c] + pp[1][c] + pp[2][c] + pp[3][c]) / den;
}

// ============================ MLP head ============================
__global__ __launch_bounds__(256) void k_head(const float* __restrict__ pooled, const float* __restrict__ fc,
                                              const float* __restrict__ nrot, const float* __restrict__ W1,
                                              const float* __restrict__ b1, const float* __restrict__ W2,
                                              const float* __restrict__ b2, const float* __restrict__ W3,
                                              const float* __restrict__ b3, const float* __restrict__ W4,
                                              const float* __restrict__ b4, float* __restrict__ out) {
    __shared__ float z[66], a1[256], a2[128], a3[64];
    const int b = blockIdx.x, tid = threadIdx.x;
    if (tid < 64) z[tid] = pooled[b * 64 + tid];
    if (tid == 64) z[64] = fc[b];
    if (tid == 65) z[65] = nrot[b];
    __syncthreads();
    float s = b1[tid];
    for (int k = 0; k < 66; ++k) s = fmaf(z[k], W1[k * 256 + tid], s);
    a1[tid] = fmaxf(s, 0.f);
    __syncthreads();
    if (tid < 128) {
        float s2 = b2[tid];
        for (int k = 0; k < 256; ++k) s2 = fmaf(a1[k], W2[k * 128 + tid], s2);
        a2[tid] = fmaxf(s2, 0.f);
    }
    __syncthreads();
    if (tid < 64) {
        float s3 = b3[tid];
        for (int k = 0; k < 128; ++k) s3 = fmaf(a2[k], W3[k * 64 + tid], s3);
        a3[tid] = fmaxf(s3, 0.f);
    }
    __syncthreads();
    if (tid < 64) {
        float p = a3[tid] * W4[tid];
        #pragma unroll
        for (int off = 32; off; off >>= 1) p += __shfl_xor(p, off);
        if (tid == 0) out[b] = p + b4[0];
    }
}

// ============================ launch ============================
extern "C" void kernel_launch(void* const* d_in, const int* in_sizes, int n_in,
                              void* d_out, int out_size, void* d_ws, size_t ws_size,
                              hipStream_t stream) {
    const float* x     = (const float*)d_in[0];
    const int*   ei    = (const int*)d_in[1];
    const float* eattr = (const float*)d_in[2];
    const float* fcv   = (const float*)d_in[3];
    const float* nrot  = (const float*)d_in[4];
    const int*   bidx  = (const int*)d_in[5];
    const float* Wl    = (const float*)d_in[6];
    const float* Wr    = (const float*)d_in[7];
    const float* We    = (const float*)d_in[8];
    const float* att   = (const float*)d_in[9];
    const float* gatb  = (const float*)d_in[10];
    const float* trW   = (const float*)d_in[11];
    const float* trb   = (const float*)d_in[12];
    const float* bng   = (const float*)d_in[13];
    const float* bnb   = (const float*)d_in[14];
    const float* gateW = (const float*)d_in[15];
    const float* W1    = (const float*)d_in[17];
    const float* b1    = (const float*)d_in[18];
    const float* W2    = (const float*)d_in[19];
    const float* b2    = (const float*)d_in[20];
    const float* W3    = (const float*)d_in[21];
    const float* b3    = (const float*)d_in[22];
    const float* W4    = (const float*)d_in[23];
    const float* b4    = (const float*)d_in[24];
    float* out = (float*)d_out;

    const int* srcv = ei;
    const int* dstv = ei + NE;

    char* w = (char*)d_ws;
    float* xl     = (float*)(w);                 // 51,200,000
    float* xragg  = (float*)(w + 51200000);      // 51,200,000 (xr in, agg out)
    float* hbuf   = (float*)(w + 102400000);     // 12,800,000
    int*   deg    = (int*)  (w + 102400000);     // overlaps hbuf (dead before first k_tr)
    int*   cnt    = (int*)  (w + 102600000);     // overlaps hbuf
    int*   eid    = (int*)  (w + 115200000);     // 1,600,000
    int*   rowptr = (int*)  (w + 116800000);     // 200,004
    float* stats  = (float*)(w + 117000064);     // 9,216 (3 * 768 * 4)
    float* pooled = (float*)(w + 117009280);     // 32,768 -> high water 117,042,048

    hipMemsetAsync(deg, 0, 400000, stream);      // deg + cnt
    hipMemsetAsync(stats, 0, 9216, stream);
    k_hist<<<(NE + 255) / 256, 256, 0, stream>>>(dstv, deg);
    k_scan<<<1, 1024, 0, stream>>>(deg, rowptr);
    k_scatter<<<(NE + 255) / 256, 256, 0, stream>>>(dstv, rowptr, cnt, eid);

    const float* hin = x;
    for (int l = 0; l < 3; ++l) {
        const float* bnp = (l == 0) ? nullptr : (stats + (l - 1) * 768);
        dim3 gg((NN + 31) / 32, 2);
        k_gemm64<<<gg, 256, 0, stream>>>(hin, Wl + l * 16384, Wr + l * 16384, xl, xragg, bnp);
        k_agg<<<2048, 256, 0, stream>>>(xl, xragg, att + l * 256, gatb + l * 256, rowptr, eid, srcv,
                                        eattr, We + l * 2048);
        k_tr<<<(NN + 127) / 128, 256, 0, stream>>>(xragg, trW + l * 16384, trb + l * 64, hbuf, stats + l * 768);
        k_bn_finalize<<<1, 256, 0, stream>>>(stats + l * 768, bng + l * 64, bnb + l * 64,
                                             (l < 2) ? (Wl + (l + 1) * 16384) : nullptr,
                                             (l < 2) ? (Wr + (l + 1) * 16384) : nullptr);
        hin = hbuf;
    }
    k_bn_apply<<<(NN * 16) / 256, 256, 0, stream>>>(hbuf, stats + 2 * 768);
    k_pool<<<NB, 256, 0, stream>>>(hbuf, gateW, bidx, pooled);
    k_head<<<NB, 256, 0, stream>>>(pooled, fcv, nrot, W1, b1, W2, b2, W3, b3, W4, b4, out);
}

// Round 3
// 789.871 us; speedup vs baseline: 1.4977x; 1.2872x over previous
//
#include <hip/hip_runtime.h>

#define NN 50000
#define NE 400000
#define NB 128
#define NINF (-__builtin_inff())

// ============================ CSR build ============================
__global__ __launch_bounds__(256) void k_hist(const int* __restrict__ dstv, int* __restrict__ deg) {
    int e = blockIdx.x * 256 + threadIdx.x;
    if (e < NE) atomicAdd(&deg[dstv[e]], 1);
}

__global__ __launch_bounds__(1024) void k_scan(const int* __restrict__ deg, int* __restrict__ rowptr) {
    __shared__ int wsum[16];
    __shared__ int total_s;
    const int tid = threadIdx.x, lane = tid & 63, w = tid >> 6;
    if (tid == 0) rowptr[0] = 0;
    int carry = 0;
    for (int base = 0; base < NN; base += 1024) {
        int i = base + tid;
        int v = (i < NN) ? deg[i] : 0;
        int incl = v;
        #pragma unroll
        for (int off = 1; off < 64; off <<= 1) {
            int t = __shfl_up(incl, off);
            if (lane >= off) incl += t;
        }
        if (lane == 63) wsum[w] = incl;
        __syncthreads();
        if (tid < 16) {
            int s = wsum[tid];
            int si = s;
            #pragma unroll
            for (int off = 1; off < 16; off <<= 1) {
                int t = __shfl_up(si, off, 16);
                if (tid >= off) si += t;
            }
            wsum[tid] = si - s;
            if (tid == 15) total_s = si;
        }
        __syncthreads();
        if (i < NN) rowptr[i + 1] = carry + wsum[w] + incl;
        carry += total_s;
        __syncthreads();
    }
}

__global__ __launch_bounds__(256) void k_scatter(const int* __restrict__ dstv, const int* __restrict__ rowptr,
                                                 int* __restrict__ cnt, int* __restrict__ eid) {
    int e = blockIdx.x * 256 + threadIdx.x;
    if (e < NE) {
        int d = dstv[e];
        int pos = rowptr[d] + atomicAdd(&cnt[d], 1);
        eid[pos] = e;
    }
}

__global__ __launch_bounds__(256) void k_permute(const int* __restrict__ eid, const int* __restrict__ srcv,
                                                 const float* __restrict__ eattr, int* __restrict__ src_perm,
                                                 float4* __restrict__ ea_perm) {
    int p = blockIdx.x * 256 + threadIdx.x;
    if (p < NE) {
        int e = eid[p];
        src_perm[p] = srcv[e];
        ea_perm[p * 2] = ((const float4*)eattr)[e * 2];
        ea_perm[p * 2 + 1] = ((const float4*)eattr)[e * 2 + 1];
    }
}

// ============================ GEMM: [N,64] @ [64,256] -> xl / xr ============================
// block: 64 rows x 128 cols, 32KB LDS. blockIdx.y: bit0 = col half, bit1 = which W.
// BN of previous layer folded: W_staged = diag(sc)*W, acc init = (sh @ W)[col]
__global__ __launch_bounds__(256) void k_gemm64(const float* __restrict__ A, const float* __restrict__ Wl,
                                                const float* __restrict__ Wr, float* __restrict__ Cl,
                                                float* __restrict__ Cr, const float* __restrict__ bnp) {
    __shared__ float Ws[64 * 128]; // 32KB
    const int mat = blockIdx.y >> 1, ch = blockIdx.y & 1;
    const float* W = mat ? Wr : Wl;
    float* C = mat ? Cr : Cl;
    for (int i = threadIdx.x; i < 2048; i += 256) {
        const int k = i >> 5, c4 = i & 31;
        float4 v = ((const float4*)W)[k * 64 + ch * 32 + c4];
        if (bnp) {
            const float s = bnp[128 + k];
            v.x *= s; v.y *= s; v.z *= s; v.w *= s;
        }
        ((float4*)Ws)[i] = v;
    }
    __syncthreads();
    const int cg = threadIdx.x & 31; // col group: cols ch*128 + cg*4 ..+3
    const int rq = threadIdx.x >> 5; // 0..7
    const int r0 = blockIdx.x * 64 + rq * 8;

    float acc[8][4];
    if (bnp) {
        const float* shW = bnp + 256 + mat * 256 + ch * 128 + cg * 4;
        #pragma unroll
        for (int rr = 0; rr < 8; ++rr) {
            acc[rr][0] = shW[0]; acc[rr][1] = shW[1]; acc[rr][2] = shW[2]; acc[rr][3] = shW[3];
        }
    } else {
        #pragma unroll
        for (int rr = 0; rr < 8; ++rr)
            acc[rr][0] = acc[rr][1] = acc[rr][2] = acc[rr][3] = 0.f;
    }

    int rowc[8];
    #pragma unroll
    for (int rr = 0; rr < 8; ++rr) {
        int r = r0 + rr;
        rowc[rr] = (r < NN) ? r : (NN - 1); // clamp loads, guard stores
    }

    for (int kq = 0; kq < 16; ++kq) {
        float4 av[8];
        #pragma unroll
        for (int rr = 0; rr < 8; ++rr)
            av[rr] = ((const float4*)A)[rowc[rr] * 16 + kq];
        #pragma unroll
        for (int kk = 0; kk < 4; ++kk) {
            const float4 w = *(const float4*)(Ws + ((kq * 4 + kk) << 7) + (cg << 2));
            #pragma unroll
            for (int rr = 0; rr < 8; ++rr) {
                const float a = reinterpret_cast<const float*>(&av[rr])[kk];
                acc[rr][0] = fmaf(a, w.x, acc[rr][0]);
                acc[rr][1] = fmaf(a, w.y, acc[rr][1]);
                acc[rr][2] = fmaf(a, w.z, acc[rr][2]);
                acc[rr][3] = fmaf(a, w.w, acc[rr][3]);
            }
        }
    }
    #pragma unroll
    for (int rr = 0; rr < 8; ++rr) {
        const int r = r0 + rr;
        if (r < NN)
            *(float4*)(C + (size_t)r * 256 + ch * 128 + cg * 4) =
                make_float4(acc[rr][0], acc[rr][1], acc[rr][2], acc[rr][3]);
    }
}

// ============================ Fused edge kernel ============================
// wave per node; lane L owns channels 4L..4L+3; We in 32 regs; prefetch pipeline.
// xragg holds xr on entry; overwritten with agg by the owning wave.
template <bool PERM>
__global__ __launch_bounds__(256, 4) void k_agg(const float* __restrict__ xl, float* __restrict__ xragg,
                                                const float* __restrict__ att, const float* __restrict__ gatb,
                                                const int* __restrict__ rowptr, const int* __restrict__ eid,
                                                const int* __restrict__ srcv, const float* __restrict__ eattr,
                                                const int* __restrict__ src_perm, const float4* __restrict__ ea_perm,
                                                const float* __restrict__ We) {
    const int lane = threadIdx.x & 63;
    const float4 we0 = ((const float4*)(We + 0 * 256))[lane];
    const float4 we1 = ((const float4*)(We + 1 * 256))[lane];
    const float4 we2 = ((const float4*)(We + 2 * 256))[lane];
    const float4 we3 = ((const float4*)(We + 3 * 256))[lane];
    const float4 we4 = ((const float4*)(We + 4 * 256))[lane];
    const float4 we5 = ((const float4*)(We + 5 * 256))[lane];
    const float4 we6 = ((const float4*)(We + 6 * 256))[lane];
    const float4 we7 = ((const float4*)(We + 7 * 256))[lane];
    const float4 attf = ((const float4*)att)[lane];
    const float4 gbf = ((const float4*)gatb)[lane];
    const int nw = gridDim.x * (blockDim.x >> 6);
    int wid = blockIdx.x * (blockDim.x >> 6) + (threadIdx.x >> 6);

    for (int n = wid; n < NN; n += nw) {
        const int e0 = rowptr[n], e1 = rowptr[n + 1];
        const float4 xr = ((const float4*)(xragg + (size_t)n * 256))[lane];
        float mrun = NINF, den = 0.f;
        float a0 = 0.f, a1 = 0.f, a2 = 0.f, a3 = 0.f;
        if (e1 > e0) {
            int s1 = 0, id1 = 0, id2 = 0;
            float4 xls_c, ea0_c, ea1_c;
            if (PERM) {
                const int s0 = src_perm[e0];
                s1 = (e0 + 1 < e1) ? src_perm[e0 + 1] : 0;
                xls_c = ((const float4*)(xl + (size_t)s0 * 256))[lane];
                ea0_c = ea_perm[(size_t)e0 * 2];
                ea1_c = ea_perm[(size_t)e0 * 2 + 1];
            } else {
                const int id0 = eid[e0];
                id1 = (e0 + 1 < e1) ? eid[e0 + 1] : 0;
                id2 = (e0 + 2 < e1) ? eid[e0 + 2] : 0;
                const int s0 = srcv[id0];
                s1 = (e0 + 1 < e1) ? srcv[id1] : 0;
                xls_c = ((const float4*)(xl + (size_t)s0 * 256))[lane];
                ea0_c = ((const float4*)(eattr + (size_t)id0 * 8))[0];
                ea1_c = ((const float4*)(eattr + (size_t)id0 * 8))[1];
            }
            for (int ei = e0; ei < e1; ++ei) {
                const bool h1 = (ei + 1 < e1), h2 = (ei + 2 < e1);
                float4 xls_n = xls_c, ea0_n = ea0_c, ea1_n = ea1_c;
                int s2 = 0, id3 = 0;
                if (h1) {
                    xls_n = ((const float4*)(xl + (size_t)s1 * 256))[lane];
                    if (PERM) {
                        ea0_n = ea_perm[(size_t)(ei + 1) * 2];
                        ea1_n = ea_perm[(size_t)(ei + 1) * 2 + 1];
                    } else {
                        ea0_n = ((const float4*)(eattr + (size_t)id1 * 8))[0];
                        ea1_n = ((const float4*)(eattr + (size_t)id1 * 8))[1];
                    }
                }
                if (h2) s2 = PERM ? src_perm[ei + 2] : srcv[id2];
                if (!PERM && (ei + 3 < e1)) id3 = eid[ei + 3];
                // ea @ We (rank-8, registers)
                float ec0 = ea0_c.x * we0.x, ec1 = ea0_c.x * we0.y, ec2 = ea0_c.x * we0.z, ec3 = ea0_c.x * we0.w;
                ec0 = fmaf(ea0_c.y, we1.x, ec0); ec1 = fmaf(ea0_c.y, we1.y, ec1); ec2 = fmaf(ea0_c.y, we1.z, ec2); ec3 = fmaf(ea0_c.y, we1.w, ec3);
                ec0 = fmaf(ea0_c.z, we2.x, ec0); ec1 = fmaf(ea0_c.z, we2.y, ec1); ec2 = fmaf(ea0_c.z, we2.z, ec2); ec3 = fmaf(ea0_c.z, we2.w, ec3);
                ec0 = fmaf(ea0_c.w, we3.x, ec0); ec1 = fmaf(ea0_c.w, we3.y, ec1); ec2 = fmaf(ea0_c.w, we3.z, ec2); ec3 = fmaf(ea0_c.w, we3.w, ec3);
                ec0 = fmaf(ea1_c.x, we4.x, ec0); ec1 = fmaf(ea1_c.x, we4.y, ec1); ec2 = fmaf(ea1_c.x, we4.z, ec2); ec3 = fmaf(ea1_c.x, we4.w, ec3);
                ec0 = fmaf(ea1_c.y, we5.x, ec0); ec1 = fmaf(ea1_c.y, we5.y, ec1); ec2 = fmaf(ea1_c.y, we5.z, ec2); ec3 = fmaf(ea1_c.y, we5.w, ec3);
                ec0 = fmaf(ea1_c.z, we6.x, ec0); ec1 = fmaf(ea1_c.z, we6.y, ec1); ec2 = fmaf(ea1_c.z, we6.z, ec2); ec3 = fmaf(ea1_c.z, we6.w, ec3);
                ec0 = fmaf(ea1_c.w, we7.x, ec0); ec1 = fmaf(ea1_c.w, we7.y, ec1); ec2 = fmaf(ea1_c.w, we7.z, ec2); ec3 = fmaf(ea1_c.w, we7.w, ec3);
                float v0 = xls_c.x + xr.x + ec0;
                float v1 = xls_c.y + xr.y + ec1;
                float v2 = xls_c.z + xr.z + ec2;
                float v3 = xls_c.w + xr.w + ec3;
                v0 = fmaxf(v0, 0.2f * v0);
                v1 = fmaxf(v1, 0.2f * v1);
                v2 = fmaxf(v2, 0.2f * v2);
                v3 = fmaxf(v3, 0.2f * v3);
                float part = v0 * attf.x;
                part = fmaf(v1, attf.y, part);
                part = fmaf(v2, attf.z, part);
                part = fmaf(v3, attf.w, part);
                part += __shfl_xor(part, 1);
                part += __shfl_xor(part, 2);
                part += __shfl_xor(part, 4);
                part += __shfl_xor(part, 8);
                const float mn = fmaxf(mrun, part);
                const float scl = __expf(mrun - mn); // first edge: exp(-inf)=0
                const float p = __expf(part - mn);
                den = fmaf(den, scl, p);
                a0 = fmaf(a0, scl, p * xls_c.x);
                a1 = fmaf(a1, scl, p * xls_c.y);
                a2 = fmaf(a2, scl, p * xls_c.z);
                a3 = fmaf(a3, scl, p * xls_c.w);
                mrun = mn;
                xls_c = xls_n; ea0_c = ea0_n; ea1_c = ea1_n;
                s1 = s2; id1 = id2; id2 = id3;
            }
        }
        const float inv = (e1 > e0) ? (1.0f / den) : 0.f;
        float4 o;
        o.x = fmaf(a0, inv, gbf.x);
        o.y = fmaf(a1, inv, gbf.y);
        o.z = fmaf(a2, inv, gbf.z);
        o.w = fmaf(a3, inv, gbf.w);
        ((float4*)(xragg + (size_t)n * 256))[lane] = o;
    }
}

// ============================ tr GEMM: [N,256]@[256,64] + bias, relu, BN stats ============================
// block: 128 rows x 64 cols; W staged in 16KB k-chunks.
__global__ __launch_bounds__(256) void k_tr(const float* __restrict__ A, const float* __restrict__ W,
                                            const float* __restrict__ bias, float* __restrict__ Hout,
                                            float* __restrict__ stats) {
    __shared__ float Ws[64 * 64]; // 16KB
    __shared__ float red[128];
    const int cg = threadIdx.x & 15; // cols cg*4..+3
    const int rq = threadIdx.x >> 4; // 0..15
    const int r0 = blockIdx.x * 128 + rq * 8;

    float acc[8][4];
    {
        const float b0 = bias[cg * 4], b1 = bias[cg * 4 + 1], b2 = bias[cg * 4 + 2], b3 = bias[cg * 4 + 3];
        #pragma unroll
        for (int rr = 0; rr < 8; ++rr) { acc[rr][0] = b0; acc[rr][1] = b1; acc[rr][2] = b2; acc[rr][3] = b3; }
    }
    int rowc[8];
    #pragma unroll
    for (int rr = 0; rr < 8; ++rr) {
        int r = r0 + rr;
        rowc[rr] = (r < NN) ? r : (NN - 1);
    }

    for (int kc = 0; kc < 4; ++kc) {
        __syncthreads(); // previous chunk fully consumed
        for (int i = threadIdx.x; i < 1024; i += 256)
            ((float4*)Ws)[i] = ((const float4*)(W + kc * 4096))[i];
        __syncthreads();
        for (int kq = 0; kq < 16; ++kq) {
            float4 av[8];
            #pragma unroll
            for (int rr = 0; rr < 8; ++rr)
                av[rr] = ((const float4*)A)[(size_t)rowc[rr] * 64 + kc * 16 + kq];
            #pragma unroll
            for (int kk = 0; kk < 4; ++kk) {
                const float4 w = *(const float4*)(Ws + ((kq * 4 + kk) << 6) + (cg << 2));
                #pragma unroll
                for (int rr = 0; rr < 8; ++rr) {
                    const float a = reinterpret_cast<const float*>(&av[rr])[kk];
                    acc[rr][0] = fmaf(a, w.x, acc[rr][0]);
                    acc[rr][1] = fmaf(a, w.y, acc[rr][1]);
                    acc[rr][2] = fmaf(a, w.z, acc[rr][2]);
                    acc[rr][3] = fmaf(a, w.w, acc[rr][3]);
                }
            }
        }
    }
    float lsum[4] = {0.f, 0.f, 0.f, 0.f}, lsq[4] = {0.f, 0.f, 0.f, 0.f};
    #pragma unroll
    for (int rr = 0; rr < 8; ++rr) {
        const int r = r0 + rr;
        if (r < NN) {
            float v0 = fmaxf(acc[rr][0], 0.f), v1 = fmaxf(acc[rr][1], 0.f);
            float v2 = fmaxf(acc[rr][2], 0.f), v3 = fmaxf(acc[rr][3], 0.f);
            lsum[0] += v0; lsum[1] += v1; lsum[2] += v2; lsum[3] += v3;
            lsq[0] = fmaf(v0, v0, lsq[0]); lsq[1] = fmaf(v1, v1, lsq[1]);
            lsq[2] = fmaf(v2, v2, lsq[2]); lsq[3] = fmaf(v3, v3, lsq[3]);
            *(float4*)(Hout + (size_t)r * 64 + cg * 4) = make_float4(v0, v1, v2, v3);
        }
    }
    __syncthreads();
    if (threadIdx.x < 128) red[threadIdx.x] = 0.f;
    __syncthreads();
    #pragma unroll
    for (int j = 0; j < 4; ++j) {
        atomicAdd(&red[cg * 4 + j], lsum[j]);
        atomicAdd(&red[64 + cg * 4 + j], lsq[j]);
    }
    __syncthreads();
    if (threadIdx.x < 64) {
        atomicAdd(&stats[threadIdx.x], red[threadIdx.x]);
        atomicAdd(&stats[64 + threadIdx.x], red[64 + threadIdx.x]);
    }
}

// stats layout per layer (stride 768): [0:64] sum, [64:128] sumsq, [128:192] sc,
// [192:256] sh, [256:512] sh@Wl_next, [512:768] sh@Wr_next
__global__ __launch_bounds__(256) void k_bn_finalize(float* __restrict__ st, const float* __restrict__ g,
                                                     const float* __restrict__ b, const float* __restrict__ Wln,
                                                     const float* __restrict__ Wrn) {
    __shared__ float sh_s[64];
    const int tid = threadIdx.x;
    if (tid < 64) {
        const float mu = st[tid] * (1.0f / (float)NN);
        const float var = st[64 + tid] * (1.0f / (float)NN) - mu * mu;
        const float rstd = rsqrtf(var + 1e-5f);
        const float sc = g[tid] * rstd;
        const float sh = fmaf(-mu, sc, b[tid]);
        st[128 + tid] = sc;
        st[192 + tid] = sh;
        sh_s[tid] = sh;
    }
    __syncthreads();
    if (Wln) {
        float al = 0.f, ar = 0.f;
        for (int k = 0; k < 64; ++k) {
            al = fmaf(sh_s[k], Wln[k * 256 + tid], al);
            ar = fmaf(sh_s[k], Wrn[k * 256 + tid], ar);
        }
        st[256 + tid] = al;
        st[512 + tid] = ar;
    }
}

// ============================ fused gate + pool (+ final BN fold) ============================
// gate logit uses gw*sc (sh·gw const cancels in softmax); pooled = raw*sc + sh since sum(w)=1.
__global__ __launch_bounds__(256) void k_pool(const float* __restrict__ h, const float* __restrict__ gw,
                                              const int* __restrict__ bidx, const float* __restrict__ st,
                                              float* __restrict__ pooled) {
    __shared__ float gate_s[1024];
    __shared__ float red[4];
    __shared__ float pp[4][64];
    const int b = blockIdx.x, tid = threadIdx.x, lane = tid & 63, w = tid >> 6;
    int lo = 0, hi = NN;
    while (lo < hi) { int mid = (lo + hi) >> 1; if (bidx[mid] < b) lo = mid + 1; else hi = mid; }
    const int s0 = lo;
    lo = 0; hi = NN;
    while (lo < hi) { int mid = (lo + hi) >> 1; if (bidx[mid] < b + 1) lo = mid + 1; else hi = mid; }
    const int s1 = lo;
    const int seg = s1 - s0;
    if (seg == 0) {
        if (tid < 64) pooled[b * 64 + tid] = st[192 + tid];
        return;
    }
    const float gwv = gw[lane] * st[128 + lane];
    for (int i = s0 + w; i < s1; i += 4) {
        float p = h[(size_t)i * 64 + lane] * gwv;
        #pragma unroll
        for (int off = 32; off; off >>= 1) p += __shfl_xor(p, off);
        if (lane == 0) gate_s[i - s0] = p;
    }
    __syncthreads();
    float v = NINF;
    for (int i = tid; i < seg; i += 256) v = fmaxf(v, gate_s[i]);
    #pragma unroll
    for (int off = 32; off; off >>= 1) v = fmaxf(v, __shfl_xor(v, off));
    if (lane == 0) red[w] = v;
    __syncthreads();
    const float mx = fmaxf(fmaxf(red[0], red[1]), fmaxf(red[2], red[3]));
    __syncthreads();
    float d = 0.f;
    for (int i = tid; i < seg; i += 256) {
        const float ex = __expf(gate_s[i] - mx);
        gate_s[i] = ex;
        d += ex;
    }
    #pragma unroll
    for (int off = 32; off; off >>= 1) d += __shfl_xor(d, off);
    if (lane == 0) red[w] = d;
    __syncthreads();
    const float den = red[0] + red[1] + red[2] + red[3];
    const int c = tid & 63, ro = tid >> 6;
    float acc = 0.f;
    for (int i = s0 + ro; i < s1; i += 4) acc = fmaf(gate_s[i - s0], h[(size_t)i * 64 + c], acc);
    pp[ro][c] = acc;
    __syncthreads();
    if (ro == 0) {
        const float raw = (pp[0][c] + pp[1][c] + pp[2][c] + pp[3][c]) / den;
        pooled[b * 64 + c] = fmaf(raw, st[128 + c], st[192 + c]);
    }
}

// ============================ MLP head ============================
__global__ __launch_bounds__(256) void k_head(const float* __restrict__ pooled, const float* __restrict__ fc,
                                              const float* __restrict__ nrot, const float* __restrict__ W1,
                                              const float* __restrict__ b1, const float* __restrict__ W2,
                                              const float* __restrict__ b2, const float* __restrict__ W3,
                                              const float* __restrict__ b3, const float* __restrict__ W4,
                                              const float* __restrict__ b4, float* __restrict__ out) {
    __shared__ float z[66], a1[256], a2[128], a3[64];
    const int b = blockIdx.x, tid = threadIdx.x;
    if (tid < 64) z[tid] = pooled[b * 64 + tid];
    if (tid == 64) z[64] = fc[b];
    if (tid == 65) z[65] = nrot[b];
    __syncthreads();
    float s = b1[tid];
    for (int k = 0; k < 66; ++k) s = fmaf(z[k], W1[k * 256 + tid], s);
    a1[tid] = fmaxf(s, 0.f);
    __syncthreads();
    if (tid < 128) {
        float s2 = b2[tid];
        for (int k = 0; k < 256; ++k) s2 = fmaf(a1[k], W2[k * 128 + tid], s2);
        a2[tid] = fmaxf(s2, 0.f);
    }
    __syncthreads();
    if (tid < 64) {
        float s3 = b3[tid];
        for (int k = 0; k < 128; ++k) s3 = fmaf(a2[k], W3[k * 64 + tid], s3);
        a3[tid] = fmaxf(s3, 0.f);
    }
    __syncthreads();
    if (tid < 64) {
        float p = a3[tid] * W4[tid];
        #pragma unroll
        for (int off = 32; off; off >>= 1) p += __shfl_xor(p, off);
        if (tid == 0) out[b] = p + b4[0];
    }
}

// ============================ launch ============================
extern "C" void kernel_launch(void* const* d_in, const int* in_sizes, int n_in,
                              void* d_out, int out_size, void* d_ws, size_t ws_size,
                              hipStream_t stream) {
    const float* x     = (const float*)d_in[0];
    const int*   ei    = (const int*)d_in[1];
    const float* eattr = (const float*)d_in[2];
    const float* fcv   = (const float*)d_in[3];
    const float* nrot  = (const float*)d_in[4];
    const int*   bidx  = (const int*)d_in[5];
    const float* Wl    = (const float*)d_in[6];
    const float* Wr    = (const float*)d_in[7];
    const float* We    = (const float*)d_in[8];
    const float* att   = (const float*)d_in[9];
    const float* gatb  = (const float*)d_in[10];
    const float* trW   = (const float*)d_in[11];
    const float* trb   = (const float*)d_in[12];
    const float* bng   = (const float*)d_in[13];
    const float* bnb   = (const float*)d_in[14];
    const float* gateW = (const float*)d_in[15];
    const float* W1    = (const float*)d_in[17];
    const float* b1    = (const float*)d_in[18];
    const float* W2    = (const float*)d_in[19];
    const float* b2    = (const float*)d_in[20];
    const float* W3    = (const float*)d_in[21];
    const float* b3    = (const float*)d_in[22];
    const float* W4    = (const float*)d_in[23];
    const float* b4    = (const float*)d_in[24];
    float* out = (float*)d_out;

    const int* srcv = ei;
    const int* dstv = ei + NE;

    char* w = (char*)d_ws;
    float*  xl       = (float*)(w);                 // 51,200,000
    float*  xragg    = (float*)(w + 51200000);      // 51,200,000 (xr in, agg out)
    float*  hbuf     = (float*)(w + 102400000);     // 12,800,000
    int*    deg      = (int*)  (w + 102400000);     // overlaps hbuf (dead before first k_tr)
    int*    cnt      = (int*)  (w + 102600000);     // overlaps hbuf
    int*    eid      = (int*)  (w + 115200000);     // 1,600,000
    int*    rowptr   = (int*)  (w + 116800000);     // 200,004
    float*  stats    = (float*)(w + 117000064);     // 9,216 (3 * 768 * 4)
    float*  pooled   = (float*)(w + 117009280);     // 32,768 -> 117,042,048
    int*    src_perm = (int*)  (w + 117042048);     // 1,600,000
    float4* ea_perm  = (float4*)(w + 118642048);    // 12,800,000 -> 131,442,048
    const bool use_perm = (ws_size >= (size_t)131442048);

    hipMemsetAsync(deg, 0, 400000, stream);         // deg + cnt
    hipMemsetAsync(stats, 0, 9216, stream);
    k_hist<<<(NE + 255) / 256, 256, 0, stream>>>(dstv, deg);
    k_scan<<<1, 1024, 0, stream>>>(deg, rowptr);
    k_scatter<<<(NE + 255) / 256, 256, 0, stream>>>(dstv, rowptr, cnt, eid);
    if (use_perm)
        k_permute<<<(NE + 255) / 256, 256, 0, stream>>>(eid, srcv, eattr, src_perm, ea_perm);

    const float* hin = x;
    for (int l = 0; l < 3; ++l) {
        const float* bnp = (l == 0) ? nullptr : (stats + (l - 1) * 768);
        dim3 gg((NN + 63) / 64, 4);
        k_gemm64<<<gg, 256, 0, stream>>>(hin, Wl + l * 16384, Wr + l * 16384, xl, xragg, bnp);
        if (use_perm)
            k_agg<true><<<2048, 256, 0, stream>>>(xl, xragg, att + l * 256, gatb + l * 256, rowptr,
                                                  eid, srcv, eattr, src_perm, ea_perm, We + l * 2048);
        else
            k_agg<false><<<2048, 256, 0, stream>>>(xl, xragg, att + l * 256, gatb + l * 256, rowptr,
                                                   eid, srcv, eattr, src_perm, ea_perm, We + l * 2048);
        k_tr<<<(NN + 127) / 128, 256, 0, stream>>>(xragg, trW + l * 16384, trb + l * 64, hbuf, stats + l * 768);
        k_bn_finalize<<<1, 256, 0, stream>>>(stats + l * 768, bng + l * 64, bnb + l * 64,
                                             (l < 2) ? (Wl + (l + 1) * 16384) : nullptr,
                                             (l < 2) ? (Wr + (l + 1) * 16384) : nullptr);
        hin = hbuf;
    }
    k_pool<<<NB, 256, 0, stream>>>(hbuf, gateW, bidx, stats + 2 * 768, pooled);
    k_head<<<NB, 256, 0, stream>>>(pooled, fcv, nrot, W1, b1, W2, b2, W3, b3, W4, b4, out);
}